// Round 3
// baseline (162.165 us; speedup 1.0000x reference)
//
#include <hip/hip_runtime.h>
#include <math.h>

// Problem constants (from reference)
#define NB 320
#define NAC 5
#define NH 26
#define NW 26
#define CHW (NH * NW)              // 676
#define KTOT (NAC * CHW)           // 3380
#define BSTRIDE (30 * CHW)         // 20280 floats per batch image
#define MAXB 50
#define CS 20
#define NMETA 20
#define DWROWS 64
#define DWDIM 1024
#define NPAIR (NMETA * NMETA)

__constant__ float c_aw[5] = {1.3221f, 3.19275f, 5.05587f, 9.47112f, 11.2364f};
__constant__ float c_ah[5] = {1.73145f, 4.00944f, 8.09892f, 4.84053f, 10.0071f};

// wave-uniform register broadcast: box data lives in lane tb's registers;
// readlane moves it to an SGPR (VALU pipe) instead of LDS broadcasts.
__device__ __forceinline__ float rl_f(float v, int l) {
    return __int_as_float(__builtin_amdgcn_readlane(__float_as_int(v), l));
}

// ---------------------------------------------------------------------------
// Fused kernel. Grid (15, 320) x 256.
//   blockIdx.x < 14 : cells path — decode + 50-box silence test + base losses
//                     for 256 cells of batch b. No LDS in the hot loop.
//   blockIdx.x == 14: boxes path (wave 0 only) — dedup scatter winners
//                     (max t = numpy last-write-wins), add (override - base +
//                     class) correction for each winner cell.
// ---------------------------------------------------------------------------
__global__ __launch_bounds__(256) void fused_k(const float* __restrict__ out,
                                               const float* __restrict__ target,
                                               float* __restrict__ loss,
                                               unsigned* __restrict__ counter) {
    int b = blockIdx.y;
    int tid = threadIdx.x;
    int lane = tid & 63;

    // per-lane box setup: lane t (t<50) holds box t of batch b
    float blox = 1e30f, bhix = -1e30f, bloy = 1e30f, bhiy = -1e30f, ba375 = 0.0f;
    float gx = 0.0f, gy = 0.0f, gw = 0.0f, gh = 0.0f;
    bool bvalid;
    {
        int t = (lane < MAXB) ? lane : 0;
        const float* g = target + b * (MAXB * 5) + t * 5;
        float g1 = g[1];
        gx = g1 * (float)NW;
        gy = g[2] * (float)NH;
        gw = g[3] * (float)NW;
        gh = g[4] * (float)NH;
        bvalid = (g1 != 0.0f) && (lane < MAXB);
        if (bvalid) {
            blox = gx - 0.5f * gw; bhix = gx + 0.5f * gw;
            bloy = gy - 0.5f * gh; bhiy = gy + 0.5f * gh;
            ba375 = 0.375f * gw * gh;   // pre-scaled: iou>0.6 <=> inter>0.375*(pa+ba)
        }
    }

    if (blockIdx.x < 14) {
        // ------------------------- cells path -------------------------
        __shared__ float sred[4];
        int k = blockIdx.x * 256 + tid;
        float contrib = 0.0f;
        if (k < KTOT) {
            int a = k / CHW;
            int rem = k - a * CHW;
            int i = rem / NW;
            int j = rem - i * NW;
            const float* cell = out + (size_t)b * BSTRIDE + a * 6 * CHW + rem;
            float rx = cell[0 * CHW];
            float ry = cell[1 * CHW];
            float w  = cell[2 * CHW];
            float h  = cell[3 * CHW];
            float rc = cell[4 * CHW];
            float x = 1.0f / (1.0f + __expf(-rx));
            float y = 1.0f / (1.0f + __expf(-ry));
            float conf = 1.0f / (1.0f + __expf(-rc));
            float pw = __expf(w) * c_aw[a];
            float ph = __expf(h) * c_ah[a];
            float px = x + (float)j;
            float py = y + (float)i;
            float plox = px - 0.5f * pw, phix = px + 0.5f * pw;
            float ploy = py - 0.5f * ph, phiy = py + 0.5f * ph;
            float thr = 0.375f * (pw * ph);
            bool silent = false;
#pragma unroll
            for (int tb = 0; tb < MAXB; tb++) {
                float t_hix = rl_f(bhix, tb), t_lox = rl_f(blox, tb);
                float t_hiy = rl_f(bhiy, tb), t_loy = rl_f(bloy, tb);
                float t_a   = rl_f(ba375, tb);
                float ix = fminf(phix, t_hix) - fmaxf(plox, t_lox);
                float iy = fminf(phiy, t_hiy) - fmaxf(ploy, t_loy);
                float inter = fmaxf(ix, 0.0f) * fmaxf(iy, 0.0f);
                silent = silent || (inter > thr + t_a);
            }
            float dx = x - 0.5f, dy = y - 0.5f;
            contrib = 0.5f * (dx * dx + dy * dy + w * w + h * h);
            if (!silent) contrib += 0.5f * conf * conf;
        }
#pragma unroll
        for (int o = 32; o > 0; o >>= 1) contrib += __shfl_down(contrib, o, 64);
        int wid = tid >> 6;
        if (lane == 0) sred[wid] = contrib;
        __syncthreads();
        if (tid == 0) atomicAdd(loss, sred[0] + sred[1] + sred[2] + sred[3]);
    } else {
        // ------------------------- boxes path -------------------------
        if (tid >= 64) return;  // single wave; no barriers below
        if (b == 0 && tid == 0)
            __hip_atomic_store(counter, 0u, __ATOMIC_RELAXED, __HIP_MEMORY_SCOPE_AGENT);
        int t = lane;
        int fidx = -1 - t;      // unique sentinel for invalid boxes
        int bn = 0, gi = 0, gj = 0;
        if (bvalid) {
            float area = gw * gh;
            float best = -1.0f;
#pragma unroll
            for (int n = 0; n < 5; n++) {
                float inter = fminf(gw, c_aw[n]) * fminf(gh, c_ah[n]);
                float iou = inter / (area + c_aw[n] * c_ah[n] - inter);
                if (iou > best) { best = iou; bn = n; }   // first max wins
            }
            gi = min(max((int)gx, 0), NW - 1);  // trunc == astype(int32) for positives
            gj = min(max((int)gy, 0), NH - 1);
            fidx = (bn * NH + gj) * NW + gi;
        }
        // winner iff no larger t' maps to the same cell (last-write-wins)
        bool winner = bvalid;
#pragma unroll
        for (int t2 = 1; t2 < MAXB; t2++) {
            int f2 = __builtin_amdgcn_readlane(fidx, t2);
            winner = winner && ((t2 <= t) || (f2 != fidx));
        }
        float contrib = 0.0f;
        if (winner) {
            int rem = gj * NW + gi;
            const float* cell = out + (size_t)b * BSTRIDE + bn * 6 * CHW + rem;
            float rx = cell[0 * CHW];
            float ry = cell[1 * CHW];
            float w  = cell[2 * CHW];
            float h  = cell[3 * CHW];
            float rc = cell[4 * CHW];
            float x = 1.0f / (1.0f + __expf(-rx));
            float y = 1.0f / (1.0f + __expf(-ry));
            float conf = 1.0f / (1.0f + __expf(-rc));
            float aw = c_aw[bn], ah = c_ah[bn];
            float pw = __expf(w) * aw;
            float ph = __expf(h) * ah;
            float px = x + (float)gi;
            float py = y + (float)gj;
            float plox = px - 0.5f * pw, phix = px + 0.5f * pw;
            float ploy = py - 0.5f * ph, phiy = py + 0.5f * ph;
            float parea = pw * ph;
            float thr = 0.375f * parea;
            // this cell's silence flag (to subtract the exact base term)
            bool silent = false;
#pragma unroll
            for (int tb = 0; tb < MAXB; tb++) {
                float t_hix = rl_f(bhix, tb), t_lox = rl_f(blox, tb);
                float t_hiy = rl_f(bhiy, tb), t_loy = rl_f(bloy, tb);
                float t_a   = rl_f(ba375, tb);
                float ix = fminf(phix, t_hix) - fmaxf(plox, t_lox);
                float iy = fminf(phiy, t_hiy) - fmaxf(ploy, t_loy);
                float inter = fmaxf(ix, 0.0f) * fmaxf(iy, 0.0f);
                silent = silent || (inter > thr + t_a);
            }
            float dx0 = x - 0.5f, dy0 = y - 0.5f;
            float base = 0.5f * (dx0 * dx0 + dy0 * dy0 + w * w + h * h);
            if (!silent) base += 0.5f * conf * conf;
            // iou_gt with own box (this lane's registers)
            float ix = fminf(phix, bhix) - fmaxf(plox, blox);
            float iy = fminf(phiy, bhiy) - fmaxf(ploy, bloy);
            float inter = fmaxf(ix, 0.0f) * fmaxf(iy, 0.0f);
            float iou = inter / (parea + gw * gh - inter);
            float txv = gx - (float)gi, tyv = gy - (float)gj;
            float twv = __logf(gw / aw), thv = __logf(gh / ah);
            float dx = x - txv, dy = y - tyv;
            float dwv = w - twv, dhv = h - thv;
            float dc = conf - iou;
            float ovr = 0.5f * (dx * dx + dy * dy + dwv * dwv + dhv * dhv) + 2.5f * dc * dc;
            // class log-softmax over the CS=20 images of this chunk
            int bs = b / CS, cs = b - bs * CS;
            const float* cl = out + (size_t)(bs * CS) * BSTRIDE + (bn * 6 + 5) * CHW + rem;
            float v[CS];
            float m = -1e30f;
#pragma unroll
            for (int c2 = 0; c2 < CS; c2++) { v[c2] = cl[(size_t)c2 * BSTRIDE]; m = fmaxf(m, v[c2]); }
            float s = 0.0f, own = 0.0f;
#pragma unroll
            for (int c2 = 0; c2 < CS; c2++) {
                s += __expf(v[c2] - m);
                if (c2 == cs) own = v[c2];
            }
            contrib = ovr - base + (m + __logf(s)) - own;
        }
#pragma unroll
        for (int o = 32; o > 0; o >>= 1) contrib += __shfl_down(contrib, o, 64);
        if (tid == 0) atomicAdd(loss, contrib);
    }
}

// ---------------------------------------------------------------------------
// meta1: enews[c][d] = mean of dw rows with id==c, plus the same-term partial
// for class c's rows. Grid (20, 4) x 256.
// ---------------------------------------------------------------------------
__global__ __launch_bounds__(256) void meta1_k(const float* __restrict__ dw,
                                               const int* __restrict__ ids,
                                               float* __restrict__ enews,
                                               float* __restrict__ loss) {
    __shared__ float sred[4];
    int c = blockIdx.x;
    int d = blockIdx.y * 256 + threadIdx.x;
    float acc = 0.0f;
    int cnt = 0;
    for (int r = 0; r < DWROWS; r++) {
        int idr = ids[r];                 // uniform -> scalar load
        float v = dw[r * DWDIM + d];
        if (idr == c) { acc += v; cnt++; }
    }
    float e = acc / fmaxf((float)cnt, 1.0f);
    enews[c * DWDIM + d] = e;
    float same = 0.0f;
    for (int r = 0; r < DWROWS; r++) {
        int idr = ids[r];
        if (idr == c) {
            float df = dw[r * DWDIM + d] - e;   // L2-hot re-read
            same += df * df;
        }
    }
#pragma unroll
    for (int o = 32; o > 0; o >>= 1) same += __shfl_down(same, o, 64);
    int lane = threadIdx.x & 63, wid = threadIdx.x >> 6;
    if (lane == 0) sred[wid] = same;
    __syncthreads();
    if (threadIdx.x == 0) atomicAdd(loss, sred[0] + sred[1] + sred[2] + sred[3]);
}

// ---------------------------------------------------------------------------
// meta2: 400 blocks compute pairwise enews distances; the last-arriving block
// (device-scope counter) computes the dmin reduction and subtracts it.
// ---------------------------------------------------------------------------
__global__ __launch_bounds__(256) void meta2_k(const int* __restrict__ ids,
                                               const float* __restrict__ enews,
                                               float* __restrict__ dmat,
                                               unsigned* __restrict__ counter,
                                               float* __restrict__ loss) {
    __shared__ float sred[4];
    __shared__ bool slast;
    __shared__ int scnt[NMETA];
    int tid = threadIdx.x;
    int p = blockIdx.x;
    int pi = p / NMETA, pj = p - pi * NMETA;
    float s = 0.0f;
    if (pi != pj) {
#pragma unroll
        for (int c = 0; c < 4; c++) {
            int d = tid + c * 256;
            float df = enews[pi * DWDIM + d] - enews[pj * DWDIM + d];
            s += df * df;
        }
    }
#pragma unroll
    for (int o = 32; o > 0; o >>= 1) s += __shfl_down(s, o, 64);
    int lane = tid & 63, wid = tid >> 6;
    if (lane == 0) sred[wid] = s;
    __syncthreads();
    if (tid == 0) {
        float tot = sred[0] + sred[1] + sred[2] + sred[3];
        __hip_atomic_store(&dmat[p], tot, __ATOMIC_RELEASE, __HIP_MEMORY_SCOPE_AGENT);
        unsigned prev = __hip_atomic_fetch_add(counter, 1u, __ATOMIC_ACQ_REL, __HIP_MEMORY_SCOPE_AGENT);
        slast = (prev == NPAIR - 1);
    }
    __syncthreads();
    if (!slast) return;
    // final block: per-class dmin over valid pairs
    if (tid < NMETA) {
        int c = 0;
        for (int r = 0; r < DWROWS; r++) c += (ids[r] == tid) ? 1 : 0;
        scnt[tid] = c;
    }
    __syncthreads();
    float dd = 0.0f;
    if (tid < NMETA && scnt[tid] > 0) {
        float dmin = INFINITY;
        bool any = false;
        for (int j = 0; j < NMETA; j++) {
            if (j != tid && scnt[j] > 0) {
                any = true;
                float dv = __hip_atomic_load(&dmat[tid * NMETA + j], __ATOMIC_ACQUIRE, __HIP_MEMORY_SCOPE_AGENT);
                dmin = fminf(dmin, dv);
            }
        }
        dd = any ? dmin : 0.0f;
    }
    if (tid < 64) {
#pragma unroll
        for (int o = 32; o > 0; o >>= 1) dd += __shfl_down(dd, o, 64);
        if (tid == 0) atomicAdd(loss, -dd);
    }
}

// ---------------------------------------------------------------------------
extern "C" void kernel_launch(void* const* d_in, const int* in_sizes, int n_in,
                              void* d_out, int out_size, void* d_ws, size_t ws_size,
                              hipStream_t stream) {
    const float* output = (const float*)d_in[0];   // (320, 30, 26, 26)
    const float* target = (const float*)d_in[1];   // (16, 20, 250) == (320, 50, 5)
    const float* dw     = (const float*)d_in[2];   // (1, 64, 1024)
    const int*   ids    = (const int*)d_in[3];     // (64,)
    float* loss = (float*)d_out;

    float* enews = (float*)d_ws;                                        // 80 KB
    float* dmat  = enews + NMETA * DWDIM;                               // 1.6 KB
    unsigned* counter = (unsigned*)(dmat + NPAIR);                      // 4 B

    hipMemsetAsync(loss, 0, sizeof(float), stream);
    dim3 grid(15, NB);
    fused_k<<<grid, 256, 0, stream>>>(output, target, loss, counter);
    dim3 g1(NMETA, DWDIM / 256);
    meta1_k<<<g1, 256, 0, stream>>>(dw, ids, enews, loss);
    meta2_k<<<NPAIR, 256, 0, stream>>>(ids, enews, dmat, counter, loss);
}

// Round 4
// 127.211 us; speedup vs baseline: 1.2748x; 1.2748x over previous
//
#include <hip/hip_runtime.h>
#include <math.h>

// Problem constants (from reference)
#define NB 320
#define NAC 5
#define NH 26
#define NW 26
#define CHW 676                    // NH*NW
#define KTOT 3380                  // NAC*CHW (divisible by 4)
#define BSTRIDE 20280              // 30*CHW floats per batch image
#define MAXB 50
#define CS 20
#define NMETA 20
#define DWROWS 64
#define DWDIM 1024
#define NPAIR (NMETA * NMETA)
#define NCBLK 4                    // cell blocks per batch, 1024 cells each
#define GX (NCBLK + 1)             // + 1 boxes block
#define NPART (NB * GX)            // 1600 fused partials
#define NPART2 (NMETA * 4)         // 80 meta1 partials

__constant__ float c_aw[5] = {1.3221f, 3.19275f, 5.05587f, 9.47112f, 11.2364f};
__constant__ float c_ah[5] = {1.73145f, 4.00944f, 8.09892f, 4.84053f, 10.0071f};

// wave-uniform register broadcast (box data lives in lane l's registers)
__device__ __forceinline__ float rl_f(float v, int l) {
    return __int_as_float(__builtin_amdgcn_readlane(__float_as_int(v), l));
}

// ---------------------------------------------------------------------------
// Fused kernel. Grid (5, 320) x 256. No atomics: each block writes part[bid].
//   blockIdx.x < 4 : cells path — 4 cells/thread (float4 plane loads),
//                    50-box silence test with readlane broadcasts amortized 4x.
//   blockIdx.x == 4: boxes path (wave 0) — scatter-winner dedup (max t =
//                    numpy last-write-wins) + override/class corrections.
// ---------------------------------------------------------------------------
__global__ __launch_bounds__(256) void fused_k(const float* __restrict__ out,
                                               const float* __restrict__ target,
                                               float* __restrict__ part,
                                               unsigned* __restrict__ counter) {
    int b = blockIdx.y;
    int tid = threadIdx.x;
    int lane = tid & 63;
    int bid = b * GX + blockIdx.x;

    // per-lane box setup: lane t (t<50) holds box t of batch b
    float blox = 1e30f, bhix = -1e30f, bloy = 1e30f, bhiy = -1e30f, ba375 = 0.0f;
    float gx = 0.0f, gy = 0.0f, gw = 0.0f, gh = 0.0f;
    bool bvalid;
    {
        int t = (lane < MAXB) ? lane : 0;
        const float* g = target + b * (MAXB * 5) + t * 5;
        float g1 = g[1];
        gx = g1 * (float)NW;
        gy = g[2] * (float)NH;
        gw = g[3] * (float)NW;
        gh = g[4] * (float)NH;
        bvalid = (g1 != 0.0f) && (lane < MAXB);
        if (bvalid) {
            blox = gx - 0.5f * gw; bhix = gx + 0.5f * gw;
            bloy = gy - 0.5f * gh; bhiy = gy + 0.5f * gh;
            ba375 = 0.375f * gw * gh;   // iou>0.6 <=> inter > 0.375*(pa+ba)
        }
    }

    if (blockIdx.x < NCBLK) {
        // ------------------------- cells path -------------------------
        __shared__ float sred[4];
        int k0 = blockIdx.x * 1024 + tid * 4;     // 4 consecutive cells
        float contrib = 0.0f;
        if (k0 < KTOT) {
            int a = k0 / CHW;
            int rem0 = k0 - a * CHW;              // 4 cells never straddle a-plane
            const float* base = out + (size_t)b * BSTRIDE + a * 6 * CHW + rem0;
            float4 R0 = *(const float4*)(base + 0 * CHW);
            float4 R1 = *(const float4*)(base + 1 * CHW);
            float4 R2 = *(const float4*)(base + 2 * CHW);
            float4 R3 = *(const float4*)(base + 3 * CHW);
            float4 R4 = *(const float4*)(base + 4 * CHW);
            float RX[4] = {R0.x, R0.y, R0.z, R0.w};
            float RY[4] = {R1.x, R1.y, R1.z, R1.w};
            float RW[4] = {R2.x, R2.y, R2.z, R2.w};
            float RH[4] = {R3.x, R3.y, R3.z, R3.w};
            float RC[4] = {R4.x, R4.y, R4.z, R4.w};
            float X[4], Y[4], CF[4];
            float PLOX[4], PHIX[4], PLOY[4], PHIY[4], THR[4];
            float aw = c_aw[a], ah = c_ah[a];
#pragma unroll
            for (int c = 0; c < 4; c++) {
                int rem = rem0 + c;
                int i = rem / NW;
                int j = rem - i * NW;
                float x = 1.0f / (1.0f + __expf(-RX[c]));
                float y = 1.0f / (1.0f + __expf(-RY[c]));
                float conf = 1.0f / (1.0f + __expf(-RC[c]));
                float pw = __expf(RW[c]) * aw;
                float ph = __expf(RH[c]) * ah;
                float px = x + (float)j;
                float py = y + (float)i;
                PLOX[c] = px - 0.5f * pw; PHIX[c] = px + 0.5f * pw;
                PLOY[c] = py - 0.5f * ph; PHIY[c] = py + 0.5f * ph;
                THR[c] = 0.375f * (pw * ph);
                X[c] = x; Y[c] = y; CF[c] = conf;
            }
            bool s0 = false, s1 = false, s2 = false, s3 = false;
#pragma unroll 5
            for (int tb = 0; tb < MAXB; tb++) {
                float thix = rl_f(bhix, tb), tlox = rl_f(blox, tb);
                float thiy = rl_f(bhiy, tb), tloy = rl_f(bloy, tb);
                float ta   = rl_f(ba375, tb);
                {
                    float ix = fminf(PHIX[0], thix) - fmaxf(PLOX[0], tlox);
                    float iy = fminf(PHIY[0], thiy) - fmaxf(PLOY[0], tloy);
                    s0 = s0 | (fmaxf(ix, 0.0f) * fmaxf(iy, 0.0f) > THR[0] + ta);
                }
                {
                    float ix = fminf(PHIX[1], thix) - fmaxf(PLOX[1], tlox);
                    float iy = fminf(PHIY[1], thiy) - fmaxf(PLOY[1], tloy);
                    s1 = s1 | (fmaxf(ix, 0.0f) * fmaxf(iy, 0.0f) > THR[1] + ta);
                }
                {
                    float ix = fminf(PHIX[2], thix) - fmaxf(PLOX[2], tlox);
                    float iy = fminf(PHIY[2], thiy) - fmaxf(PLOY[2], tloy);
                    s2 = s2 | (fmaxf(ix, 0.0f) * fmaxf(iy, 0.0f) > THR[2] + ta);
                }
                {
                    float ix = fminf(PHIX[3], thix) - fmaxf(PLOX[3], tlox);
                    float iy = fminf(PHIY[3], thiy) - fmaxf(PLOY[3], tloy);
                    s3 = s3 | (fmaxf(ix, 0.0f) * fmaxf(iy, 0.0f) > THR[3] + ta);
                }
            }
            bool sil[4] = {s0, s1, s2, s3};
#pragma unroll
            for (int c = 0; c < 4; c++) {
                float dx = X[c] - 0.5f, dy = Y[c] - 0.5f;
                contrib += 0.5f * (dx * dx + dy * dy + RW[c] * RW[c] + RH[c] * RH[c]);
                if (!sil[c]) contrib += 0.5f * CF[c] * CF[c];
            }
        }
#pragma unroll
        for (int o = 32; o > 0; o >>= 1) contrib += __shfl_down(contrib, o, 64);
        int wid = tid >> 6;
        if (lane == 0) sred[wid] = contrib;
        __syncthreads();
        if (tid == 0) part[bid] = sred[0] + sred[1] + sred[2] + sred[3];
    } else {
        // ------------------------- boxes path -------------------------
        if (tid >= 64) return;  // single wave
        if (b == 0 && tid == 0)
            __hip_atomic_store(counter, 0u, __ATOMIC_RELAXED, __HIP_MEMORY_SCOPE_AGENT);
        int t = lane;
        int fidx = -1 - t;      // unique sentinel for invalid boxes
        int bn = 0, gi = 0, gj = 0;
        if (bvalid) {
            float area = gw * gh;
            float best = -1.0f;
#pragma unroll
            for (int n = 0; n < 5; n++) {
                float inter = fminf(gw, c_aw[n]) * fminf(gh, c_ah[n]);
                float iou = inter / (area + c_aw[n] * c_ah[n] - inter);
                if (iou > best) { best = iou; bn = n; }   // first max wins
            }
            gi = min(max((int)gx, 0), NW - 1);  // trunc == astype(int32), vals >= 0
            gj = min(max((int)gy, 0), NH - 1);
            fidx = (bn * NH + gj) * NW + gi;
        }
        // winner iff no larger t' maps to the same cell (last-write-wins)
        bool winner = bvalid;
        for (int t2 = 1; t2 < MAXB; t2++) {
            int f2 = __builtin_amdgcn_readlane(fidx, t2);
            winner = winner && ((t2 <= t) || (f2 != fidx));
        }
        float contrib = 0.0f;
        if (winner) {
            int rem = gj * NW + gi;
            const float* cell = out + (size_t)b * BSTRIDE + bn * 6 * CHW + rem;
            float rx = cell[0 * CHW];
            float ry = cell[1 * CHW];
            float w  = cell[2 * CHW];
            float h  = cell[3 * CHW];
            float rc = cell[4 * CHW];
            float x = 1.0f / (1.0f + __expf(-rx));
            float y = 1.0f / (1.0f + __expf(-ry));
            float conf = 1.0f / (1.0f + __expf(-rc));
            float aw = c_aw[bn], ah = c_ah[bn];
            float pw = __expf(w) * aw;
            float ph = __expf(h) * ah;
            float px = x + (float)gi;
            float py = y + (float)gj;
            float plox = px - 0.5f * pw, phix = px + 0.5f * pw;
            float ploy = py - 0.5f * ph, phiy = py + 0.5f * ph;
            float parea = pw * ph;
            float thr = 0.375f * parea;
            bool silent = false;
            for (int tb = 0; tb < MAXB; tb++) {
                float thix = rl_f(bhix, tb), tlox = rl_f(blox, tb);
                float thiy = rl_f(bhiy, tb), tloy = rl_f(bloy, tb);
                float ta   = rl_f(ba375, tb);
                float ix = fminf(phix, thix) - fmaxf(plox, tlox);
                float iy = fminf(phiy, thiy) - fmaxf(ploy, tloy);
                silent = silent | (fmaxf(ix, 0.0f) * fmaxf(iy, 0.0f) > thr + ta);
            }
            float dx0 = x - 0.5f, dy0 = y - 0.5f;
            float base = 0.5f * (dx0 * dx0 + dy0 * dy0 + w * w + h * h);
            if (!silent) base += 0.5f * conf * conf;
            // iou_gt with own box (this lane's registers)
            float ix = fminf(phix, bhix) - fmaxf(plox, blox);
            float iy = fminf(phiy, bhiy) - fmaxf(ploy, bloy);
            float inter = fmaxf(ix, 0.0f) * fmaxf(iy, 0.0f);
            float iou = inter / (parea + gw * gh - inter);
            float txv = gx - (float)gi, tyv = gy - (float)gj;
            float twv = __logf(gw / aw), thv = __logf(gh / ah);
            float dx = x - txv, dy = y - tyv;
            float dwv = w - twv, dhv = h - thv;
            float dc = conf - iou;
            float ovr = 0.5f * (dx * dx + dy * dy + dwv * dwv + dhv * dhv) + 2.5f * dc * dc;
            // class log-softmax over the CS=20 images of this chunk
            int bs = b / CS, cs = b - bs * CS;
            const float* cl = out + (size_t)(bs * CS) * BSTRIDE + (bn * 6 + 5) * CHW + rem;
            float v[CS];
            float m = -1e30f;
#pragma unroll
            for (int c2 = 0; c2 < CS; c2++) { v[c2] = cl[(size_t)c2 * BSTRIDE]; m = fmaxf(m, v[c2]); }
            float s = 0.0f, own = 0.0f;
#pragma unroll
            for (int c2 = 0; c2 < CS; c2++) {
                s += __expf(v[c2] - m);
                if (c2 == cs) own = v[c2];
            }
            contrib = ovr - base + (m + __logf(s)) - own;
        }
#pragma unroll
        for (int o = 32; o > 0; o >>= 1) contrib += __shfl_down(contrib, o, 64);
        if (tid == 0) part[bid] = contrib;
    }
}

// ---------------------------------------------------------------------------
// meta1: enews means + same-term in ONE dw pass (sum(v-e)^2 = sum v^2 - cnt e^2).
// Grid (20, 4) x 256 -> part2[80].
// ---------------------------------------------------------------------------
__global__ __launch_bounds__(256) void meta1_k(const float* __restrict__ dw,
                                               const int* __restrict__ ids,
                                               float* __restrict__ enews,
                                               float* __restrict__ part2) {
    __shared__ float sred[4];
    int c = blockIdx.x;
    int d = blockIdx.y * 256 + threadIdx.x;
    float acc = 0.0f, ssq = 0.0f;
    int cnt = 0;
    for (int r = 0; r < DWROWS; r++) {
        int idr = ids[r];                 // uniform -> scalar load
        float v = dw[r * DWDIM + d];
        if (idr == c) { acc += v; ssq += v * v; cnt++; }
    }
    float e = acc / fmaxf((float)cnt, 1.0f);
    enews[c * DWDIM + d] = e;
    float same = ssq - (float)cnt * e * e;
#pragma unroll
    for (int o = 32; o > 0; o >>= 1) same += __shfl_down(same, o, 64);
    int lane = threadIdx.x & 63, wid = threadIdx.x >> 6;
    if (lane == 0) sred[wid] = same;
    __syncthreads();
    if (threadIdx.x == 0) part2[c * 4 + blockIdx.y] = sred[0] + sred[1] + sred[2] + sred[3];
}

// ---------------------------------------------------------------------------
// meta2: 400 blocks compute pairwise enews distances; last-arriving block
// computes dmin, sums ALL partials (part[1600]+part2[80]), writes loss[0].
// ---------------------------------------------------------------------------
__global__ __launch_bounds__(256) void meta2_k(const int* __restrict__ ids,
                                               const float* __restrict__ enews,
                                               float* __restrict__ dmat,
                                               unsigned* __restrict__ counter,
                                               const float* __restrict__ partbuf,
                                               float* __restrict__ loss) {
    __shared__ float sred[4];
    __shared__ bool slast;
    __shared__ int scnt[NMETA];
    __shared__ float sdd;
    int tid = threadIdx.x;
    int p = blockIdx.x;
    int pi = p / NMETA, pj = p - pi * NMETA;
    float s = 0.0f;
    if (pi != pj) {
#pragma unroll
        for (int c = 0; c < 4; c++) {
            int d = tid + c * 256;
            float df = enews[pi * DWDIM + d] - enews[pj * DWDIM + d];
            s += df * df;
        }
    }
#pragma unroll
    for (int o = 32; o > 0; o >>= 1) s += __shfl_down(s, o, 64);
    int lane = tid & 63, wid = tid >> 6;
    if (lane == 0) sred[wid] = s;
    __syncthreads();
    if (tid == 0) {
        float tot = sred[0] + sred[1] + sred[2] + sred[3];
        __hip_atomic_store(&dmat[p], tot, __ATOMIC_RELEASE, __HIP_MEMORY_SCOPE_AGENT);
        unsigned prev = __hip_atomic_fetch_add(counter, 1u, __ATOMIC_ACQ_REL, __HIP_MEMORY_SCOPE_AGENT);
        slast = (prev == NPAIR - 1);
    }
    __syncthreads();
    if (!slast) return;
    // --- final block ---
    if (tid < NMETA) {
        int c = 0;
        for (int r = 0; r < DWROWS; r++) c += (ids[r] == tid) ? 1 : 0;
        scnt[tid] = c;
    }
    __syncthreads();
    float dd = 0.0f;
    if (tid < NMETA && scnt[tid] > 0) {
        float dmin = INFINITY;
        bool any = false;
        for (int j = 0; j < NMETA; j++) {
            if (j != tid && scnt[j] > 0) {
                any = true;
                float dv = __hip_atomic_load(&dmat[tid * NMETA + j], __ATOMIC_ACQUIRE, __HIP_MEMORY_SCOPE_AGENT);
                dmin = fminf(dmin, dv);
            }
        }
        dd = any ? dmin : 0.0f;
    }
    if (tid < 64) {
#pragma unroll
        for (int o = 32; o > 0; o >>= 1) dd += __shfl_down(dd, o, 64);
        if (tid == 0) sdd = dd;
    }
    // sum the 1680 partial losses
    float ps = 0.0f;
    for (int i2 = tid; i2 < NPART + NPART2; i2 += 256) ps += partbuf[i2];
#pragma unroll
    for (int o = 32; o > 0; o >>= 1) ps += __shfl_down(ps, o, 64);
    if (lane == 0) sred[wid] = ps;
    __syncthreads();
    if (tid == 0) loss[0] = (sred[0] + sred[1] + sred[2] + sred[3]) - sdd;
}

// ---------------------------------------------------------------------------
extern "C" void kernel_launch(void* const* d_in, const int* in_sizes, int n_in,
                              void* d_out, int out_size, void* d_ws, size_t ws_size,
                              hipStream_t stream) {
    const float* output = (const float*)d_in[0];   // (320, 30, 26, 26)
    const float* target = (const float*)d_in[1];   // (16, 20, 250) == (320, 50, 5)
    const float* dw     = (const float*)d_in[2];   // (1, 64, 1024)
    const int*   ids    = (const int*)d_in[3];     // (64,)
    float* loss = (float*)d_out;

    float* enews = (float*)d_ws;                    // 80 KB
    float* dmat  = enews + NMETA * DWDIM;           // 1.6 KB
    float* part  = dmat + NPAIR;                    // 1600 floats (fused partials)
    float* part2 = part + NPART;                    // 80 floats (meta1 partials)
    unsigned* counter = (unsigned*)(part2 + NPART2);

    dim3 grid(GX, NB);
    fused_k<<<grid, 256, 0, stream>>>(output, target, part, counter);
    dim3 g1(NMETA, DWDIM / 256);
    meta1_k<<<g1, 256, 0, stream>>>(dw, ids, enews, part2);
    meta2_k<<<NPAIR, 256, 0, stream>>>(ids, enews, dmat, counter, part, loss);
}